// Round 6
// baseline (201.444 us; speedup 1.0000x reference)
//
#include <hip/hip_runtime.h>

#define USER_COUNT 100000
#define ITEM_COUNT 50000
#define N_NODES    150000   // USER_COUNT + ITEM_COUNT
#define EMB        64
#define N_EDGES    1250000
#define BATCH      4096

#define NBKT      147                 // ceil(150000 / 1024), bucket = row >> 10
#define BROWS     1024                // rows per bucket
#define A1_TILE   2048
#define A1_BLOCKS ((N_EDGES + A1_TILE - 1) / A1_TILE)   // 611
#define COLMASK   0x3FFFFu
#define ROW_ALLOC 150536              // >= NBKT*BROWS (150528), 16B padded
#define NLIST_PAD 150016

// bf16x2 pack/unpack (round-to-nearest-even; inputs are finite)
static __device__ __forceinline__ unsigned pack_bf16x2(float a, float b) {
    unsigned ua = __float_as_uint(a);
    unsigned ub = __float_as_uint(b);
    ua += 0x7FFFu + ((ua >> 16) & 1u);
    ub += 0x7FFFu + ((ub >> 16) & 1u);
    return (ua >> 16) | (ub & 0xFFFF0000u);
}
static __device__ __forceinline__ float2 unpack_bf16x2(unsigned v) {
    float2 r;
    r.x = __uint_as_float(v << 16);
    r.y = __uint_as_float(v & 0xFFFF0000u);
    return r;
}

// Shared SpMM row body: accumulate sum_e w_e * x[col_e] for dims (2l, 2l+1),
// unroll 4 for memory-level parallelism (avg degree ~8.3).
static __device__ __forceinline__ float2 spmm_row(const uint2* __restrict__ edges,
                                                  int s, int e,
                                                  const unsigned* __restrict__ xin,
                                                  int l) {
    float ax0 = 0.f, ay0 = 0.f, ax1 = 0.f, ay1 = 0.f;
    float ax2 = 0.f, ay2 = 0.f, ax3 = 0.f, ay3 = 0.f;
    int i = s;
    for (; i + 3 < e; i += 4) {
        uint2 e0 = edges[i];
        uint2 e1 = edges[i + 1];
        uint2 e2 = edges[i + 2];
        uint2 e3 = edges[i + 3];
        float w0 = __uint_as_float(e0.y);
        float w1 = __uint_as_float(e1.y);
        float w2 = __uint_as_float(e2.y);
        float w3 = __uint_as_float(e3.y);
        float2 v0 = unpack_bf16x2(xin[(size_t)(e0.x & COLMASK) * 32 + l]);
        float2 v1 = unpack_bf16x2(xin[(size_t)(e1.x & COLMASK) * 32 + l]);
        float2 v2 = unpack_bf16x2(xin[(size_t)(e2.x & COLMASK) * 32 + l]);
        float2 v3 = unpack_bf16x2(xin[(size_t)(e3.x & COLMASK) * 32 + l]);
        ax0 += w0 * v0.x; ay0 += w0 * v0.y;
        ax1 += w1 * v1.x; ay1 += w1 * v1.y;
        ax2 += w2 * v2.x; ay2 += w2 * v2.y;
        ax3 += w3 * v3.x; ay3 += w3 * v3.y;
    }
    for (; i < e; ++i) {
        uint2 e0 = edges[i];
        float w0 = __uint_as_float(e0.y);
        float2 v0 = unpack_bf16x2(xin[(size_t)(e0.x & COLMASK) * 32 + l]);
        ax0 += w0 * v0.x; ay0 += w0 * v0.y;
    }
    return make_float2((ax0 + ax1) + (ax2 + ax3), (ay0 + ay1) + (ay2 + ay3));
}

// ---------------------------------------------------------------------------
// x0 = concat(user_emb, item_emb) -> bf16x2-packed table
// ---------------------------------------------------------------------------
__global__ void k_concat_bf16(const float* __restrict__ ue,
                              const float* __restrict__ ie,
                              unsigned* __restrict__ x) {
    const size_t nu4 = (size_t)USER_COUNT * EMB / 4;
    const size_t nt4 = (size_t)N_NODES   * EMB / 4;
    size_t i = (size_t)blockIdx.x * blockDim.x + threadIdx.x;
    if (i >= nt4) return;
    float4 v = (i < nu4) ? ((const float4*)ue)[i] : ((const float4*)ie)[i - nu4];
    uint2 p;
    p.x = pack_bf16x2(v.x, v.y);
    p.y = pack_bf16x2(v.z, v.w);
    ((uint2*)x)[i] = p;
}

// ---------------------------------------------------------------------------
// Bucket histogram (147 buckets), LDS-staged
// ---------------------------------------------------------------------------
__global__ void k_bhist(const int* __restrict__ row, int* __restrict__ gcount) {
    __shared__ int h[NBKT];
    int tid = threadIdx.x;
    if (tid < NBKT) h[tid] = 0;
    __syncthreads();
    int base = blockIdx.x * 1024;
    #pragma unroll
    for (int j = 0; j < 4; ++j) {
        int e = base + j * 256 + tid;
        if (e < N_EDGES) atomicAdd(&h[row[e] >> 10], 1);
    }
    __syncthreads();
    if (tid < NBKT && h[tid]) atomicAdd(&gcount[tid], h[tid]);
}

// ---------------------------------------------------------------------------
// Scan of 147 bucket counts -> gstart (exclusive) and gcursor copy.
// Only tid<=NBKT may write (round-4 bugfix).
// ---------------------------------------------------------------------------
__global__ void k_bscan(const int* __restrict__ gcount,
                        int* __restrict__ gstart, int* __restrict__ gcursor) {
    __shared__ int sA[256], sB[256];
    int tid = threadIdx.x;
    int v = (tid < NBKT) ? gcount[tid] : 0;
    sA[tid] = v;
    __syncthreads();
    int* in = sA; int* out = sB;
    for (int off = 1; off < 256; off <<= 1) {
        out[tid] = in[tid] + ((tid >= off) ? in[tid - off] : 0);
        __syncthreads();
        int* t = in; in = out; out = t;
    }
    int excl = in[tid] - v;       // tid == NBKT: == N_EDGES (sentinel)
    if (tid <= NBKT) {
        gstart[tid]  = excl;
        gcursor[tid] = excl;
    }
}

// ---------------------------------------------------------------------------
// Pass A1: bucket-sort edges into edges_a with coherent (staged) writes.
// Record: {col | (row&1023)<<18, w_f32}
// ---------------------------------------------------------------------------
__global__ void k_binfill(const int* __restrict__ row, const int* __restrict__ col,
                          const float* __restrict__ w,
                          int* __restrict__ gcursor, uint2* __restrict__ edges_a) {
    __shared__ int cnt[256], cnt2[NBKT], gpos[NBKT], sc[NBKT];
    __shared__ int sA[256], sB[256];
    __shared__ uint2 srec[A1_TILE];
    __shared__ int  sdst[A1_TILE];
    int tid = threadIdx.x;
    cnt[tid] = 0;
    if (tid < NBKT) cnt2[tid] = 0;
    __syncthreads();

    int ebase   = blockIdx.x * A1_TILE;
    int tilecnt = min(A1_TILE, N_EDGES - ebase);

    int r[8], c[8]; float wv[8];
    #pragma unroll
    for (int j = 0; j < 8; ++j) {
        int e = ebase + j * 256 + tid;
        if (e < N_EDGES) {
            r[j] = row[e]; c[j] = col[e]; wv[j] = w[e];
            atomicAdd(&cnt[r[j] >> 10], 1);
        } else {
            r[j] = -1;
        }
    }
    __syncthreads();

    int* in = sA; int* out = sB;
    in[tid] = cnt[tid];
    __syncthreads();
    for (int off = 1; off < 256; off <<= 1) {
        out[tid] = in[tid] + ((tid >= off) ? in[tid - off] : 0);
        __syncthreads();
        int* t = in; in = out; out = t;
    }
    if (tid < NBKT) {
        sc[tid]   = in[tid] - cnt[tid];
        gpos[tid] = atomicAdd(&gcursor[tid], cnt[tid]);
    }
    __syncthreads();

    #pragma unroll
    for (int j = 0; j < 8; ++j) {
        if (r[j] >= 0) {
            int b  = r[j] >> 10;
            int lp = sc[b] + atomicAdd(&cnt2[b], 1);
            srec[lp] = make_uint2((unsigned)c[j] | ((unsigned)(r[j] & 1023) << 18),
                                  __float_as_uint(wv[j]));
            sdst[lp] = gpos[b] + (lp - sc[b]);
        }
    }
    __syncthreads();

    #pragma unroll
    for (int j = 0; j < 8; ++j) {
        int i = j * 256 + tid;
        if (i < tilecnt) edges_a[sdst[i]] = srec[i];
    }
}

// ---------------------------------------------------------------------------
// Pass A2: per-bucket exact CSR (block-local writes, no cross-XCD sharing)
// ---------------------------------------------------------------------------
__global__ __launch_bounds__(512) void k_csrfill(const int* __restrict__ gstart,
                                                 const uint2* __restrict__ edges_a,
                                                 uint2* __restrict__ edges_b,
                                                 int* __restrict__ row_start) {
    __shared__ int hist[BROWS], cur[BROWS];
    __shared__ int sA[BROWS], sB[BROWS];
    int tid   = threadIdx.x;
    int b     = blockIdx.x;
    int base  = gstart[b];
    int count = gstart[b + 1] - base;

    hist[tid] = 0; hist[tid + 512] = 0;
    __syncthreads();
    for (int i = tid; i < count; i += 512) {
        unsigned a = edges_a[base + i].x;
        atomicAdd(&hist[(a >> 18) & 1023], 1);
    }
    __syncthreads();

    int* in = sA; int* out = sB;
    in[tid] = hist[tid]; in[tid + 512] = hist[tid + 512];
    __syncthreads();
    for (int off = 1; off < 1024; off <<= 1) {
        out[tid] = in[tid] + ((tid >= off) ? in[tid - off] : 0);
        int i2 = tid + 512;
        out[i2] = in[i2] + ((i2 >= off) ? in[i2 - off] : 0);
        __syncthreads();
        int* t = in; in = out; out = t;
    }
    #pragma unroll
    for (int k = 0; k < 2; ++k) {
        int rl   = tid + k * 512;
        int excl = in[rl] - hist[rl];
        row_start[b * BROWS + rl] = base + excl;
        cur[rl] = base + excl;
    }
    __syncthreads();

    for (int i = tid; i < count; i += 512) {
        uint2 rec = edges_a[base + i];
        int rl  = (rec.x >> 18) & 1023;
        int pos = atomicAdd(&cur[rl], 1);
        edges_b[pos] = rec;
    }
}

// ---------------------------------------------------------------------------
// Mark nodes whose x2 is needed: the selected nodes + cols of their edges
// ---------------------------------------------------------------------------
__global__ void k_mark(const int* __restrict__ users, const int* __restrict__ items,
                       const int* __restrict__ row_start,
                       const uint2* __restrict__ edges_b,
                       unsigned char* __restrict__ flag) {
    int t = blockIdx.x * blockDim.x + threadIdx.x;
    int g = t >> 3;
    int l = t & 7;
    if (g >= 2 * BATCH) return;
    int node = (g < BATCH) ? users[g] : USER_COUNT + items[g - BATCH];
    if (l == 0) flag[node] = 1;
    int s = row_start[node], e = row_start[node + 1];
    for (int i = s + l; i < e; i += 8)
        flag[edges_b[i].x & COLMASK] = 1;
}

// ---------------------------------------------------------------------------
// Ballot-compaction of flagged nodes into a dense list
// ---------------------------------------------------------------------------
__global__ void k_compact(const unsigned char* __restrict__ flag,
                          int* __restrict__ list, int* __restrict__ count) {
    int i = blockIdx.x * blockDim.x + threadIdx.x;
    bool p = (i < N_NODES) && flag[i];
    unsigned long long m = __ballot(p);
    int lane = threadIdx.x & 63;
    int base = 0;
    if (lane == 0 && m) base = atomicAdd(count, __popcll(m));
    base = __shfl(base, 0);
    if (p) {
        int pos = base + __popcll(m & ((1ull << lane) - 1ull));
        list[pos] = i;
    }
}

// ---------------------------------------------------------------------------
// Full gather SpMM: 32-lane group per node, lane owns 2 dims.
// ---------------------------------------------------------------------------
__global__ void k_spmm_bf16(const int* __restrict__ row_start,
                            const uint2* __restrict__ edges,
                            const unsigned* __restrict__ xin,
                            unsigned* __restrict__ xout) {
    int g = blockIdx.x * (blockDim.x >> 5) + (threadIdx.x >> 5);
    int l = threadIdx.x & 31;
    if (g >= N_NODES) return;
    float2 a = spmm_row(edges, row_start[g], row_start[g + 1], xin, l);
    xout[(size_t)g * 32 + l] = pack_bf16x2(a.x, a.y);
}

// ---------------------------------------------------------------------------
// List-driven gather SpMM (layer 2 prune): only compacted rows
// ---------------------------------------------------------------------------
__global__ void k_spmm_list(const int* __restrict__ row_start,
                            const uint2* __restrict__ edges,
                            const unsigned* __restrict__ xin,
                            unsigned* __restrict__ xout,
                            const int* __restrict__ list,
                            const int* __restrict__ count) {
    int gi = blockIdx.x * (blockDim.x >> 5) + (threadIdx.x >> 5);
    if (gi >= *count) return;
    int g = list[gi];
    int l = threadIdx.x & 31;
    float2 a = spmm_row(edges, row_start[g], row_start[g + 1], xin, l);
    xout[(size_t)g * 32 + l] = pack_bf16x2(a.x, a.y);
}

// ---------------------------------------------------------------------------
// out[g] = 0.25*(ego_f32[node] + x1[node] + x2[node])
// ---------------------------------------------------------------------------
__global__ void k_gather_base(const int* __restrict__ users,
                              const int* __restrict__ items,
                              const float* __restrict__ ue,
                              const float* __restrict__ ie,
                              const unsigned* __restrict__ x1,
                              const unsigned* __restrict__ x2,
                              float* __restrict__ out) {
    int g = blockIdx.x * (blockDim.x >> 5) + (threadIdx.x >> 5);
    int l = threadIdx.x & 31;
    if (g >= 2 * BATCH) return;
    int node = (g < BATCH) ? users[g] : USER_COUNT + items[g - BATCH];
    const float* ego = (node < USER_COUNT)
                         ? ue + (size_t)node * EMB
                         : ie + (size_t)(node - USER_COUNT) * EMB;
    float2 e = ((const float2*)ego)[l];
    float2 a = unpack_bf16x2(x1[(size_t)node * 32 + l]);
    float2 b = unpack_bf16x2(x2[(size_t)node * 32 + l]);
    float2 r;
    r.x = 0.25f * (e.x + a.x + b.x);
    r.y = 0.25f * (e.y + a.y + b.y);
    ((float2*)out)[(size_t)g * 32 + l] = r;
}

// ---------------------------------------------------------------------------
// Layer-3 SpMM only at the 8192 selected nodes, fused into out +=
// ---------------------------------------------------------------------------
__global__ void k_out_spmm(const int* __restrict__ users,
                           const int* __restrict__ items,
                           const int* __restrict__ row_start,
                           const uint2* __restrict__ edges,
                           const unsigned* __restrict__ xin,
                           float* __restrict__ out) {
    int g = blockIdx.x * (blockDim.x >> 5) + (threadIdx.x >> 5);
    int l = threadIdx.x & 31;
    if (g >= 2 * BATCH) return;
    int node = (g < BATCH) ? users[g] : USER_COUNT + items[g - BATCH];
    float2 a = spmm_row(edges, row_start[node], row_start[node + 1], xin, l);
    float2* o = (float2*)out + (size_t)g * 32 + l;
    float2 cur = *o;
    cur.x += 0.25f * a.x;
    cur.y += 0.25f * a.y;
    *o = cur;
}

extern "C" void kernel_launch(void* const* d_in, const int* in_sizes, int n_in,
                              void* d_out, int out_size, void* d_ws, size_t ws_size,
                              hipStream_t stream) {
    const float* user_emb    = (const float*)d_in[0];
    const float* item_emb    = (const float*)d_in[1];
    const int*   edge_row    = (const int*)d_in[2];
    const int*   edge_col    = (const int*)d_in[3];
    const float* edge_weight = (const float*)d_in[4];
    const int*   users       = (const int*)d_in[5];
    const int*   items       = (const int*)d_in[6];
    float* out = (float*)d_out;

    // ws layout
    const size_t node_u32 = (size_t)N_NODES * 32;     // 19.2 MB per table
    unsigned* xa        = (unsigned*)d_ws;            // ego (bf16)
    unsigned* xb        = xa + node_u32;              // x1
    unsigned* xc        = xb + node_u32;              // x2 (pruned rows only)
    int*      row_start = (int*)(xc + node_u32);      // ROW_ALLOC ints
    int*      gcount    = row_start + ROW_ALLOC;      // 256
    int*      gstart    = gcount + 256;               // 256
    int*      gcursor   = gstart + 256;               // 256
    int*      ncount    = gcursor + 256;              // 16
    int*      nlist     = ncount + 16;                // NLIST_PAD
    unsigned char* flag = (unsigned char*)(nlist + NLIST_PAD);   // 150528 bytes
    uint2*    edges_a   = (uint2*)(flag + 150528);    // 10 MB
    uint2*    edges_b   = edges_a + N_EDGES;          // 10 MB
    // total ~79 MB

    // x0 -> bf16 table
    {
        size_t n4 = (size_t)N_NODES * EMB / 4;
        int blocks = (int)((n4 + 255) / 256);
        k_concat_bf16<<<blocks, 256, 0, stream>>>(user_emb, item_emb, xa);
    }

    // ---------- CSR build (write-coherent, 2-level) ----------
    hipMemsetAsync(gcount, 0, 256 * sizeof(int), stream);
    hipMemsetAsync(ncount, 0, 16 * sizeof(int), stream);
    hipMemsetAsync(flag, 0, 150528, stream);
    {
        int blocks = (N_EDGES + 1023) / 1024;
        k_bhist<<<blocks, 256, 0, stream>>>(edge_row, gcount);
    }
    k_bscan<<<1, 256, 0, stream>>>(gcount, gstart, gcursor);
    k_binfill<<<A1_BLOCKS, 256, 0, stream>>>(edge_row, edge_col, edge_weight,
                                             gcursor, edges_a);
    k_csrfill<<<NBKT, 512, 0, stream>>>(gstart, edges_a, edges_b, row_start);

    // ---------- mark + compact (needed x2 rows) ----------
    k_mark<<<(2 * BATCH * 8 + 255) / 256, 256, 0, stream>>>(users, items, row_start,
                                                            edges_b, flag);
    k_compact<<<(N_NODES + 255) / 256, 256, 0, stream>>>(flag, nlist, ncount);

    // ---------- layers ----------
    const int spmm_blocks = (N_NODES + 7) / 8;
    k_spmm_bf16<<<spmm_blocks, 256, 0, stream>>>(row_start, edges_b, xa, xb);
    k_spmm_list<<<spmm_blocks, 256, 0, stream>>>(row_start, edges_b, xb, xc,
                                                 nlist, ncount);

    // ---------- epilogue ----------
    const int ep_blocks = (2 * BATCH + 7) / 8;
    k_gather_base<<<ep_blocks, 256, 0, stream>>>(users, items, user_emb, item_emb,
                                                 xb, xc, out);
    k_out_spmm<<<ep_blocks, 256, 0, stream>>>(users, items, row_start, edges_b,
                                              xc, out);
}